// Round 1
// 148.698 us; speedup vs baseline: 1.0197x; 1.0197x over previous
//
#include <hip/hip_runtime.h>
#include <stdint.h>

// Problem constants (B,C,D,H,W) = (2,1,128,256,256)
#define BB 2
#define DD 128
#define HH 256
#define WW 256
static constexpr int64_t N = (int64_t)BB * DD * HH * WW;   // 16,777,216
static constexpr int WPR    = WW / 64;                     // 4 words per row
static constexpr int NWORDS = BB * DD * HH * WPR;          // 262,144 words (2 MB)
static constexpr int K1_BLOCKS = NWORDS / 16;              // 16384 (4 rows/block)
static constexpr int K2_BLOCKS = (HH / 16) * (DD / 16) * (BB * WPR); // 1024

__device__ __forceinline__ uint64_t shfl_xor_u64(uint64_t v, int lanemask) {
    int lo = __shfl_xor((int)(uint32_t)v, lanemask, 64);
    int hi = __shfl_xor((int)(v >> 32), lanemask, 64);
    return ((uint64_t)(uint32_t)hi << 32) | (uint32_t)lo;
}

// ---------------------------------------------------------------------------
// K1: fused predicate + X-dilation (radius 3, bit-packed) AND base L1 sum.
// One wave = one W-row. Lane l loads float4 l of the target row -> nibble,
// X-dilation via 12-bit window from lane+-1 nibbles, butterfly pack to u64.
// Also loads the input row and accumulates sum(|t-i|) -> per-block double.
// Reads 128 MiB (the ONLY full-volume pass), writes 2 MB mask + partials.
// ---------------------------------------------------------------------------
__global__ __launch_bounds__(256) void mask_xdil_sum(const float* __restrict__ tgt,
                                                     const float* __restrict__ inp,
                                                     uint64_t* __restrict__ mask,
                                                     double* __restrict__ p0) {
    const int wave = threadIdx.x >> 6;
    const int lane = threadIdx.x & 63;
    const int row  = blockIdx.x * 4 + wave;             // 65,536 rows total

    const int64_t base = (int64_t)row * WW;
    float4 t = ((const float4*)(tgt + base))[lane];
    float4 a = ((const float4*)(inp + base))[lane];

    // base L1 term (weight-independent): sum |t - i| over the full volume
    float s = fabsf(t.x - a.x) + fabsf(t.y - a.y)
            + fabsf(t.z - a.z) + fabsf(t.w - a.w);

    unsigned nib = 0;
    nib |= (t.x > 0.0f && t.x < 1.0f) ? 1u : 0u;
    nib |= (t.y > 0.0f && t.y < 1.0f) ? 2u : 0u;
    nib |= (t.z > 0.0f && t.z < 1.0f) ? 4u : 0u;
    nib |= (t.w > 0.0f && t.w < 1.0f) ? 8u : 0u;

    unsigned L = (unsigned)__shfl_up((int)nib, 1, 64);
    unsigned R = (unsigned)__shfl_down((int)nib, 1, 64);
    if (lane == 0)  L = 0;
    if (lane == 63) R = 0;

    // 12-bit window: bit b <-> voxel 4l-4+b. Own voxel j at b=4+j;
    // dilation radius 3 -> OR of window bits [j+1, j+7].
    const unsigned m = L | (nib << 4) | (R << 8);
    unsigned dil = 0;
    #pragma unroll
    for (int j = 0; j < 4; j++)
        dil |= ((m & (0x7Fu << (j + 1))) ? 1u : 0u) << j;

    // butterfly pack: 16 nibbles -> one u64 per 16-lane group
    uint64_t x = dil;
    #pragma unroll
    for (int st = 0; st < 4; st++) {
        const int sh = 4 << st;                // 4, 8, 16, 32
        uint64_t p = shfl_xor_u64(x, 1 << st);
        x = (lane & (1 << st)) ? (p | (x << sh)) : (x | (p << sh));
    }
    if ((lane & 15) == 0)
        mask[(int64_t)row * WPR + (lane >> 4)] = x;

    // block-reduce s -> double partial
    #pragma unroll
    for (int off = 32; off > 0; off >>= 1)
        s += __shfl_down(s, off, 64);
    __shared__ float wsum[4];
    if (lane == 0) wsum[wave] = s;
    __syncthreads();
    if (threadIdx.x == 0)
        p0[blockIdx.x] = (double)((wsum[0] + wsum[1]) + (wsum[2] + wsum[3]));
}

// ---------------------------------------------------------------------------
// K2: fused Y+Z dilation (radius 3 each) + residual reduction.
// Block = 16x16 (y,z) words for fixed (b,wx). Raw 22x22 halo tile ->
// y-dilate -> z-dilate into a register word v. loss*N = 11*S0 - 10*SA where
// SA = sum_{dilated==0} |t-i|. Each thread owns one output word (16 voxels):
// if v == all-ones (the overwhelmingly common case) it contributes nothing
// and issues ZERO data loads; otherwise it fetches only the needed float4s.
// The dilated mask is never written to memory. Worst case degrades to the
// old full second pass; for this data it is ~2 MB of mask traffic total.
// ---------------------------------------------------------------------------
__global__ __launch_bounds__(256) void yz_dil_reduce(const uint64_t* __restrict__ in,
                                                     const float* __restrict__ inp,
                                                     const float* __restrict__ tgt,
                                                     double* __restrict__ p1) {
    __shared__ uint64_t raw[22][23];   // +1 pad
    __shared__ uint64_t yd[22][17];    // +1 pad
    const int ty = threadIdx.x & 15;
    const int tz = threadIdx.x >> 4;
    const int y0 = blockIdx.x * 16;
    const int z0 = blockIdx.y * 16;
    const int b  = blockIdx.z >> 2;
    const int wx = blockIdx.z & 3;

    for (int idx = threadIdx.x; idx < 22 * 22; idx += 256) {
        const int zz = idx / 22, yy = idx % 22;
        const int gz = z0 - 3 + zz, gy = y0 - 3 + yy;
        uint64_t v = 0;
        if (gz >= 0 && gz < DD && gy >= 0 && gy < HH)
            v = in[(((int64_t)(b * DD + gz)) * HH + gy) * WPR + wx];
        raw[zz][yy] = v;
    }
    __syncthreads();

    for (int idx = threadIdx.x; idx < 22 * 16; idx += 256) {
        const int zz = idx >> 4, yy = idx & 15;
        uint64_t v = 0;
        #pragma unroll
        for (int d = 0; d < 7; d++) v |= raw[zz][yy + d];
        yd[zz][yy] = v;
    }
    __syncthreads();

    uint64_t v = 0;
    #pragma unroll
    for (int d = 0; d < 7; d++) v |= yd[tz + d][ty];

    // residual: |t-i| at voxels whose dilated mask bit is 0
    float sab = 0.0f;
    if (v != ~0ull) {
        const int64_t wi = (((int64_t)(b * DD + z0 + tz)) * HH + y0 + ty) * WPR + wx;
        const float4* a4 = (const float4*)inp;
        const float4* t4 = (const float4*)tgt;
        #pragma unroll 1
        for (int q = 0; q < 16; q++) {
            const unsigned nb = (unsigned)(v >> (q * 4)) & 0xFu;
            if (nb != 0xFu) {
                float4 aa = a4[wi * 16 + q];
                float4 tt = t4[wi * 16 + q];
                if (!(nb & 1u)) sab += fabsf(tt.x - aa.x);
                if (!(nb & 2u)) sab += fabsf(tt.y - aa.y);
                if (!(nb & 4u)) sab += fabsf(tt.z - aa.z);
                if (!(nb & 8u)) sab += fabsf(tt.w - aa.w);
            }
        }
    }

    #pragma unroll
    for (int off = 32; off > 0; off >>= 1)
        sab += __shfl_down(sab, off, 64);
    __shared__ float ws[4];
    const int lane = threadIdx.x & 63;
    const int wv   = threadIdx.x >> 6;
    if (lane == 0) ws[wv] = sab;
    __syncthreads();
    if (threadIdx.x == 0) {
        const int flat = blockIdx.x + gridDim.x * (blockIdx.y + gridDim.y * blockIdx.z);
        p1[flat] = (double)((ws[0] + ws[1]) + (ws[2] + ws[3]));
    }
}

// ---------------------------------------------------------------------------
// K3: sum partials; out = (11*S0 - 10*SA) / N.
// ---------------------------------------------------------------------------
__global__ __launch_bounds__(1024) void finalize(const double* __restrict__ p0,
                                                 const double* __restrict__ p1,
                                                 float* __restrict__ out) {
    double s0 = 0.0, sa = 0.0;
    for (int i = threadIdx.x; i < K1_BLOCKS; i += 1024) s0 += p0[i];
    for (int i = threadIdx.x; i < K2_BLOCKS; i += 1024) sa += p1[i];
    #pragma unroll
    for (int off = 32; off > 0; off >>= 1) {
        s0 += __shfl_down(s0, off, 64);
        sa += __shfl_down(sa, off, 64);
    }
    __shared__ double w0[16], wa[16];
    const int lane = threadIdx.x & 63;
    const int wv   = threadIdx.x >> 6;
    if (lane == 0) { w0[wv] = s0; wa[wv] = sa; }
    __syncthreads();
    if (threadIdx.x == 0) {
        double S0 = 0.0, SA = 0.0;
        #pragma unroll
        for (int k = 0; k < 16; k++) { S0 += w0[k]; SA += wa[k]; }
        out[0] = (float)((11.0 * S0 - 10.0 * SA) / (double)N);
    }
}

extern "C" void kernel_launch(void* const* d_in, const int* in_sizes, int n_in,
                              void* d_out, int out_size, void* d_ws, size_t ws_size,
                              hipStream_t stream) {
    const float* inp = (const float*)d_in[0];   // "input"
    const float* tgt = (const float*)d_in[1];   // "target"
    float* out = (float*)d_out;

    // workspace layout (every region fully written each run; no poison reads)
    double*   p0    = (double*)d_ws;                           // 16384 doubles = 128 KB
    double*   p1    = (double*)((char*)d_ws + 144 * 1024);     // 1024 doubles = 8 KB
    uint64_t* mask0 = (uint64_t*)((char*)d_ws + 256 * 1024);   // 2 MB

    mask_xdil_sum<<<K1_BLOCKS, 256, 0, stream>>>(tgt, inp, mask0, p0);
    yz_dil_reduce<<<dim3(HH / 16, DD / 16, BB * WPR), 256, 0, stream>>>(mask0, inp, tgt, p1);
    finalize<<<1, 1024, 0, stream>>>(p0, p1, out);
}